// Round 1
// 405.293 us; speedup vs baseline: 1.1035x; 1.1035x over previous
//
#include <hip/hip_runtime.h>
#include <hip/hip_bf16.h>

#define D_MODEL 1024
#define D_INNER 2048
#define NTOK    16384   // B*T = 4*4096
#define TLEN    4096
#define LN_EPS  1e-5f

typedef unsigned short u16;
typedef unsigned short u16x4 __attribute__((ext_vector_type(4)));
typedef unsigned short u16x8 __attribute__((ext_vector_type(8)));
typedef __bf16        bf16x8 __attribute__((ext_vector_type(8)));
typedef float         f32x4  __attribute__((ext_vector_type(4)));

__device__ __forceinline__ float b2f(u16 u) {
    union { float f; unsigned int i; } v; v.i = ((unsigned int)u) << 16; return v.f;
}
__device__ __forceinline__ u16 f2b(float f) {
    union { float f; unsigned int i; } v; v.f = f;
    unsigned int r = v.i + 0x7fffu + ((v.i >> 16) & 1u);  // RNE
    return (u16)(r >> 16);
}

// async global->LDS, 16B per lane. LDS dest = wave-uniform base + lane*16.
__device__ __forceinline__ void gld_lds16(const u16* g, u16* l) {
    __builtin_amdgcn_global_load_lds(
        (const __attribute__((address_space(1))) void*)g,
        (__attribute__((address_space(3))) void*)l, 16, 0, 0);
}

// ---------------- LayerNorm body (fp32 in, bf16 out), one block per row ----------------
__device__ __forceinline__ void ln_body(
    int row, int tid,
    const float* __restrict__ x, const float* __restrict__ gamma,
    const float* __restrict__ beta, u16* __restrict__ xn)
{
    const float* xr = x + (size_t)row * D_MODEL;
    const int c0 = tid * 4;

    f32x4 xv = *(const f32x4*)(xr + c0);
    float s = 0.f, s2 = 0.f;
#pragma unroll
    for (int i = 0; i < 4; i++) { s += xv[i]; s2 += xv[i] * xv[i]; }

#pragma unroll
    for (int off = 32; off > 0; off >>= 1) {
        s  += __shfl_down(s,  off);
        s2 += __shfl_down(s2, off);
    }
    __shared__ float red[8];
    const int wave = tid >> 6, lane = tid & 63;
    if (lane == 0) { red[wave] = s; red[4 + wave] = s2; }
    __syncthreads();
    const float ts  = red[0] + red[1] + red[2] + red[3];
    const float ts2 = red[4] + red[5] + red[6] + red[7];
    const float mu  = ts * (1.0f / D_MODEL);
    const float var = ts2 * (1.0f / D_MODEL) - mu * mu;
    const float inv = rsqrtf(var + LN_EPS);

    f32x4 gv = *(const f32x4*)(gamma + c0);
    f32x4 bv = *(const f32x4*)(beta + c0);
    u16x4 out;
#pragma unroll
    for (int i = 0; i < 4; i++)
        out[i] = f2b((xv[i] - mu) * inv * gv[i] + bv[i]);
    *(u16x4*)(xn + (size_t)row * D_MODEL + c0) = out;
}

// ---------------- merged prep: LN (lnRows rows) + W cvt + conv_w transpose ----------------
__global__ __launch_bounds__(256) void prep_kernel(
    const float* __restrict__ x, const float* __restrict__ gamma,
    const float* __restrict__ beta, u16* __restrict__ xn,
    const float* __restrict__ W_in, u16* __restrict__ wbin,
    const float* __restrict__ W_out, u16* __restrict__ wbout,
    const float* __restrict__ conv_w, float* __restrict__ wt,
    int lnRows)
{
    const int b   = blockIdx.x;
    const int tid = threadIdx.x;

    if (b < lnRows) {
        ln_body(b, tid, x, gamma, beta, xn);
        return;
    }
    int rb = b - lnRows;
    if (rb < 4096) {                       // W_in convert
        const int o = (rb * 256 + tid) * 4;
        f32x4 v = *(const f32x4*)(W_in + o);
        u16x4 w;
#pragma unroll
        for (int j = 0; j < 4; j++) w[j] = f2b(v[j]);
        *(u16x4*)(wbin + o) = w;
        return;
    }
    rb -= 4096;
    if (rb < 2048) {                       // W_out convert
        const int o = (rb * 256 + tid) * 4;
        f32x4 v = *(const f32x4*)(W_out + o);
        u16x4 w;
#pragma unroll
        for (int j = 0; j < 4; j++) w[j] = f2b(v[j]);
        *(u16x4*)(wbout + o) = w;
        return;
    }
    rb -= 2048;                            // conv_w transpose (32 blocks)
    const int i = rb * 256 + tid;          // 0..8191
    const int ch = i >> 2, j = i & 3;
    wt[j * D_INNER + ch] = conv_w[i];
}

// ---------------- standalone LN (chunked fallback path) ----------------
__global__ __launch_bounds__(256) void ln_kernel(
    const float* __restrict__ x, const float* __restrict__ gamma,
    const float* __restrict__ beta, u16* __restrict__ xn)
{
    ln_body(blockIdx.x, threadIdx.x, x, gamma, beta, xn);
}

// =====================================================================================
// 256x256 8-phase GEMM: C[M,N] = A[M,K] * Bt[N,K]^T (+fp32 residual)
// 512 thr = 8 waves (2M x 4N), per-wave 128x64 out, BK=64, 2 K-tiles/iter.
// LDS 128 KiB double-buffer; XOR-swizzled global_load_lds source so
// LDS[row][chunk] = G[row][chunk^(row&7)]; ds_read_b128 fragments conflict-free.
// Pipeline (per 4-phase tile block; all barriers raw s_barrier, counted vmcnt):
//   p1: ds A-Mh0(8)+B-Nh0(4); stage next A-odd     ; MFMA Q(0,0)
//   p2: ds B-Nh1(4)         ; stage t+2 A-even     ; MFMA Q(0,2)
//   p3: ds A-Mh1(8)         ; stage t+2 B-even     ; MFMA Q(4,0)
//   p4:                       stage t+2 B-odd      ; MFMA Q(4,2); vmcnt(6)
// Safety: staged region's last ds_read is >=1 barrier before stage issue
// (A-even freed after p1, B-even p1, B-odd p2, A-odd p3).
// =====================================================================================
#define BAR()      __builtin_amdgcn_s_barrier()
#define LGKM0()    asm volatile("s_waitcnt lgkmcnt(0)" ::: "memory")
#define WAIT_VM6() asm volatile("s_waitcnt vmcnt(6)" ::: "memory")
#define WAIT_VM0() asm volatile("s_waitcnt vmcnt(0)" ::: "memory")

#define STAGE_A(ldsb, s0, s1, kt) do { \
    gld_lds16(Ag + (size_t)(s0) * K + (kt) + goff, &(ldsb)[(s0) * 64]); \
    gld_lds16(Ag + (size_t)(s1) * K + (kt) + goff, &(ldsb)[(s1) * 64]); \
} while (0)
#define STAGE_B(ldsb, s0, s1, kt) do { \
    gld_lds16(Bg + (size_t)(s0) * K + (kt) + goff, &(ldsb)[(s0) * 64]); \
    gld_lds16(Bg + (size_t)(s1) * K + (kt) + goff, &(ldsb)[(s1) * 64]); \
} while (0)

#define RD_A(base, roff) do { \
    _Pragma("unroll") for (int m_ = 0; m_ < 4; m_++) { \
        const u16* p_ = (base) + (arow0 + (roff) + m_ * 16) * 64; \
        aF[m_][0] = __builtin_bit_cast(bf16x8, *(const u16x8*)(p_ + cx0)); \
        aF[m_][1] = __builtin_bit_cast(bf16x8, *(const u16x8*)(p_ + cx1)); \
    } } while (0)
#define RD_B(base, dst, roff) do { \
    _Pragma("unroll") for (int n_ = 0; n_ < 2; n_++) { \
        const u16* p_ = (base) + (brow0 + (roff) + n_ * 16) * 64; \
        dst[n_][0] = __builtin_bit_cast(bf16x8, *(const u16x8*)(p_ + cx0)); \
        dst[n_][1] = __builtin_bit_cast(bf16x8, *(const u16x8*)(p_ + cx1)); \
    } } while (0)

#define MMA_Q(m0, n0, BB) do { \
    _Pragma("unroll") for (int m_ = 0; m_ < 4; m_++) \
    _Pragma("unroll") for (int n_ = 0; n_ < 2; n_++) \
    _Pragma("unroll") for (int k_ = 0; k_ < 2; k_++) \
        acc[(m0) + m_][(n0) + n_] = __builtin_amdgcn_mfma_f32_16x16x32_bf16( \
            aF[m_][k_], BB[n_][k_], acc[(m0) + m_][(n0) + n_], 0, 0, 0); \
} while (0)

template<bool OUT_F32>
__global__ __launch_bounds__(512, 2) void gemm256(
    const u16* __restrict__ A, const u16* __restrict__ Bt,
    void* __restrict__ Cv, const float* __restrict__ Res,
    int M, int N, int K)
{
    __shared__ u16 As[2][256 * 64];
    __shared__ u16 Bs[2][256 * 64];

    const int tid  = threadIdx.x;
    const int wave = tid >> 6;
    const int lane = tid & 63;
    const int wm = wave >> 2, wn = wave & 3;
    const int lane15 = lane & 15, quad = lane >> 4;

    // bijective XCD-aware swizzle (all launch grids have nwg % 8 == 0)
    const int gx   = gridDim.x;
    const int nwg  = gx * gridDim.y;
    const int flat = blockIdx.y * gx + blockIdx.x;
    const int q8   = nwg >> 3;
    const int swz  = (flat & 7) * q8 + (flat >> 3);
    const int bm = swz % gx, bn = swz / gx;

    const u16* Ag = A  + (size_t)bm * 256 * K;
    const u16* Bg = Bt + (size_t)bn * 256 * K;

    // staging: per lane source offset (XOR-swizzled column chunk)
    const int lrow = lane >> 3;                       // 0..7
    const int lcol = ((lane & 7) ^ lrow) * 8;
    const size_t goff = (size_t)lrow * K + lcol;

    // slab bases (wave-uniform) for each half-tile class
    const int aEv0 = wave * 8,      aEv1 = 128 + wave * 8;
    const int aOd0 = 64 + wave * 8, aOd1 = 192 + wave * 8;
    const int bEv0 = (wave >> 2) * 64 + (wave & 3) * 8, bEv1 = 128 + bEv0;
    const int bOd0 = bEv0 + 32,     bOd1 = bEv1 + 32;

    // fragment-read constants
    const int arow0 = wm * 128 + lane15;
    const int brow0 = wn * 64  + lane15;
    const int sw8   = lane15 & 7;
    const int cx0   = ((quad ^ sw8) << 3);   // chunk c=quad
    const int cx1   = cx0 ^ 32;              // chunk c=quad+4

    f32x4  acc[8][4] = {};
    bf16x8 aF[4][2], bE[2][2], bO[2][2];

    const int NT = K >> 6;       // K-tiles (even for K=1024/2048)
    const int NI = NT >> 1;

    // ---- prologue: tile0 full -> buf0; tile1 first 3 halves -> buf1
    STAGE_A(As[0], aEv0, aEv1, 0);
    STAGE_B(Bs[0], bEv0, bEv1, 0);
    STAGE_B(Bs[0], bOd0, bOd1, 0);
    STAGE_A(As[0], aOd0, aOd1, 0);
    STAGE_A(As[1], aEv0, aEv1, 64);
    STAGE_B(Bs[1], bEv0, bEv1, 64);
    STAGE_B(Bs[1], bOd0, bOd1, 64);
    WAIT_VM6();                 // tile0 landed; tile1's 3 halves in flight
    BAR();

    for (int i = 0; i < NI; i++) {
        const int kt0   = i * 128;
        const bool more = (i + 1 < NI);
#pragma unroll
        for (int h = 0; h < 2; h++) {
            const u16* as = As[h];
            const u16* bs = Bs[h];
            const int ktA = kt0 + 64  + h * 64;   // tile 2i+1+h (A-odd, buf h^1)
            const int ktS = kt0 + 128 + h * 64;   // tile 2i+2+h (p2-p4, buf h)
            const bool gA = (h == 0) || more;
            const bool gS = more;

            // ---- phase 1: Q(0,0)
            RD_A(as, 0);
            RD_B(bs, bE, 0);
            if (gA) STAGE_A(As[h ^ 1], aOd0, aOd1, ktA);
            BAR(); LGKM0();
            __builtin_amdgcn_s_setprio(1);
            MMA_Q(0, 0, bE);
            __builtin_amdgcn_s_setprio(0);
            BAR();

            // ---- phase 2: Q(0,2)
            RD_B(bs, bO, 32);
            if (gS) STAGE_A(As[h], aEv0, aEv1, ktS);
            BAR(); LGKM0();
            __builtin_amdgcn_s_setprio(1);
            MMA_Q(0, 2, bO);
            __builtin_amdgcn_s_setprio(0);
            BAR();

            // ---- phase 3: Q(4,0)
            RD_A(as, 64);
            if (gS) STAGE_B(Bs[h], bEv0, bEv1, ktS);
            BAR(); LGKM0();
            __builtin_amdgcn_s_setprio(1);
            MMA_Q(4, 0, bE);
            __builtin_amdgcn_s_setprio(0);
            BAR();

            // ---- phase 4: Q(4,2) + counted drain
            if (gS) STAGE_B(Bs[h], bOd0, bOd1, ktS);
            BAR(); LGKM0();
            __builtin_amdgcn_s_setprio(1);
            MMA_Q(4, 2, bO);
            __builtin_amdgcn_s_setprio(0);
            if (more)       WAIT_VM6();   // next tile fully landed, 3 halves in flight
            else if (h == 0) WAIT_VM0();  // last iteration: drain for final tile
            BAR();
        }
    }

    // ---- epilogue: C[row = quad*4+i][col = lane15] per 16x16 subtile
    const int m0 = bm * 256 + wm * 128 + quad * 4;
    const int n0 = bn * 256 + wn * 64 + lane15;
#pragma unroll
    for (int mf = 0; mf < 8; mf++) {
#pragma unroll
        for (int nf = 0; nf < 4; nf++) {
#pragma unroll
            for (int i = 0; i < 4; i++) {
                const int r  = m0 + mf * 16 + i;
                const int cc = n0 + nf * 16;
                const size_t idx = (size_t)r * N + cc;
                float v = acc[mf][nf][i];
                if (OUT_F32) {
                    ((float*)Cv)[idx] = v + Res[idx];
                } else {
                    ((u16*)Cv)[idx] = f2b(v);
                }
            }
        }
    }
}

// ---------------- causal depthwise conv (d_conv=4) + silu(x)*silu(z) ----------------
__global__ __launch_bounds__(256) void conv_gate8(
    const u16* __restrict__ xz, const float* __restrict__ wt,
    const float* __restrict__ conv_b, u16* __restrict__ y)
{
    const int tid  = threadIdx.x;
    const int row0 = blockIdx.x * 8;
    const int c    = tid * 8;
    const int t0   = row0 & (TLEN - 1);

    float w[4][8];
#pragma unroll
    for (int j = 0; j < 4; j++) {
        f32x4 a = *(const f32x4*)(wt + j * D_INNER + c);
        f32x4 b = *(const f32x4*)(wt + j * D_INNER + c + 4);
#pragma unroll
        for (int u = 0; u < 4; u++) { w[j][u] = a[u]; w[j][4 + u] = b[u]; }
    }
    float bias[8];
    {
        f32x4 a = *(const f32x4*)(conv_b + c);
        f32x4 b = *(const f32x4*)(conv_b + c + 4);
#pragma unroll
        for (int u = 0; u < 4; u++) { bias[u] = a[u]; bias[4 + u] = b[u]; }
    }

    u16x8 xv[11];
    if (t0 != 0) {
#pragma unroll
        for (int k = 0; k < 3; k++)
            xv[k] = *(const u16x8*)(xz + (size_t)(row0 - 3 + k) * 4096 + c);
    } else {
#pragma unroll
        for (int k = 0; k < 3; k++) xv[k] = (u16x8)0;
    }
#pragma unroll
    for (int k = 3; k < 11; k++)
        xv[k] = *(const u16x8*)(xz + (size_t)(row0 - 3 + k) * 4096 + c);

#pragma unroll
    for (int i = 0; i < 8; i++) {
        float acc[8];
#pragma unroll
        for (int u = 0; u < 8; u++) acc[u] = bias[u];
#pragma unroll
        for (int j = 0; j < 4; j++)
#pragma unroll
            for (int u = 0; u < 8; u++)
                acc[u] += b2f(xv[i + j][u]) * w[j][u];

        u16x8 zv = *(const u16x8*)(xz + (size_t)(row0 + i) * 4096 + 2048 + c);
        u16x8 out;
#pragma unroll
        for (int u = 0; u < 8; u++) {
            const float a = acc[u];
            const float z = b2f(zv[u]);
            const float sa = a / (1.0f + __expf(-a));
            const float sz = z / (1.0f + __expf(-z));
            out[u] = f2b(sa * sz);
        }
        *(u16x8*)(y + (size_t)(row0 + i) * (size_t)D_INNER + c) = out;
    }
}

extern "C" void kernel_launch(void* const* d_in, const int* in_sizes, int n_in,
                              void* d_out, int out_size, void* d_ws, size_t ws_size,
                              hipStream_t stream)
{
    const float* x      = (const float*)d_in[0];
    const float* gamma  = (const float*)d_in[1];
    const float* beta   = (const float*)d_in[2];
    const float* W_in   = (const float*)d_in[3];  // [4096, 1024] fp32
    const float* conv_w = (const float*)d_in[4];  // [2048, 1, 4] fp32
    const float* conv_b = (const float*)d_in[5];  // [2048] fp32
    const float* W_out  = (const float*)d_in[6];  // [1024, 2048] fp32
    float* out = (float*)d_out;

    const int nWin  = 4096 * 1024;
    const int nWout = 1024 * 2048;
    const int nWc   = D_INNER * 4;            // 8192

    u16*   wbin  = (u16*)d_ws;                // bf16 W_in
    u16*   wbout = wbin + nWin;               // bf16 W_out
    float* wt    = (float*)(wbout + nWout);   // fp32 [4][2048] conv weights
    u16*   base  = (u16*)(wt + nWc);

    // Workspace-adaptive chunking (whole batches -> conv halo never crosses).
    const size_t wbytes = (size_t)(nWin + nWout) * sizeof(u16) + nWc * sizeof(float);
    const size_t perRow = (size_t)(D_MODEL + 4096 + D_INNER) * sizeof(u16);
    int NC = 4;
    if (ws_size >= wbytes + (size_t)NTOK * perRow)          NC = 1;
    else if (ws_size >= wbytes + (size_t)(NTOK/2) * perRow) NC = 2;
    const int RC = NTOK / NC;

    u16* xn = base;                               // RC*1024
    u16* xz = xn + (size_t)RC * D_MODEL;          // RC*4096
    u16* y  = xz + (size_t)RC * 4096;             // RC*2048

    // 0. merged prep: weight cvt (+ full LN when NC==1) — one launch
    const int lnRows = (NC == 1) ? NTOK : 0;
    prep_kernel<<<lnRows + 4096 + 2048 + 32, 256, 0, stream>>>(
        x, gamma, beta, xn, W_in, wbin, W_out, wbout, conv_w, wt, lnRows);

    for (int c = 0; c < NC; c++) {
        const float* xc   = x   + (size_t)c * RC * D_MODEL;
        float*       outc = out + (size_t)c * RC * D_MODEL;

        // 1. LayerNorm (only needed per-chunk when NC>1)
        if (NC > 1)
            ln_kernel<<<RC, 256, 0, stream>>>(xc, gamma, beta, xn);

        // 2. in_proj: xz[RC,4096] = xn[RC,1024] @ W_in^T  (bf16 out)
        dim3 g1(RC / 256, (2 * D_INNER) / 256);
        gemm256<false><<<g1, 512, 0, stream>>>(xn, wbin, xz, nullptr,
                                               RC, 2 * D_INNER, D_MODEL);

        // 3. causal depthwise conv + silu gating (8 tokens/thread)
        conv_gate8<<<RC / 8, 256, 0, stream>>>(xz, wt, conv_b, y);

        // 4. out_proj + residual: out[RC,1024] = x + y[RC,2048] @ W_out^T (fp32 out)
        dim3 g2(RC / 256, D_MODEL / 256);
        gemm256<true><<<g2, 512, 0, stream>>>(y, wbout, outc, xc,
                                              RC, D_MODEL, D_INNER);
    }
}

// Round 2
// 400.949 us; speedup vs baseline: 1.1154x; 1.0108x over previous
//
#include <hip/hip_runtime.h>
#include <hip/hip_bf16.h>

#define D_MODEL 1024
#define D_INNER 2048
#define NTOK    16384   // B*T = 4*4096
#define TLEN    4096
#define LN_EPS  1e-5f

typedef unsigned short u16;
typedef unsigned short u16x4 __attribute__((ext_vector_type(4)));
typedef unsigned short u16x8 __attribute__((ext_vector_type(8)));
typedef __bf16        bf16x8 __attribute__((ext_vector_type(8)));
typedef float         f32x4  __attribute__((ext_vector_type(4)));

__device__ __forceinline__ float b2f(u16 u) {
    union { float f; unsigned int i; } v; v.i = ((unsigned int)u) << 16; return v.f;
}
__device__ __forceinline__ u16 f2b(float f) {
    union { float f; unsigned int i; } v; v.f = f;
    unsigned int r = v.i + 0x7fffu + ((v.i >> 16) & 1u);  // RNE
    return (u16)(r >> 16);
}

// async global->LDS, 16B per lane. LDS dest = wave-uniform base + lane*16.
__device__ __forceinline__ void gld_lds16(const u16* g, u16* l) {
    __builtin_amdgcn_global_load_lds(
        (const __attribute__((address_space(1))) void*)g,
        (__attribute__((address_space(3))) void*)l, 16, 0, 0);
}

// ---------------- LayerNorm body (fp32 in, bf16 out), one block per row ----------------
__device__ __forceinline__ void ln_body(
    int row, int tid,
    const float* __restrict__ x, const float* __restrict__ gamma,
    const float* __restrict__ beta, u16* __restrict__ xn)
{
    const float* xr = x + (size_t)row * D_MODEL;
    const int c0 = tid * 4;

    f32x4 xv = *(const f32x4*)(xr + c0);
    float s = 0.f, s2 = 0.f;
#pragma unroll
    for (int i = 0; i < 4; i++) { s += xv[i]; s2 += xv[i] * xv[i]; }

#pragma unroll
    for (int off = 32; off > 0; off >>= 1) {
        s  += __shfl_down(s,  off);
        s2 += __shfl_down(s2, off);
    }
    __shared__ float red[8];
    const int wave = tid >> 6, lane = tid & 63;
    if (lane == 0) { red[wave] = s; red[4 + wave] = s2; }
    __syncthreads();
    const float ts  = red[0] + red[1] + red[2] + red[3];
    const float ts2 = red[4] + red[5] + red[6] + red[7];
    const float mu  = ts * (1.0f / D_MODEL);
    const float var = ts2 * (1.0f / D_MODEL) - mu * mu;
    const float inv = rsqrtf(var + LN_EPS);

    f32x4 gv = *(const f32x4*)(gamma + c0);
    f32x4 bv = *(const f32x4*)(beta + c0);
    u16x4 out;
#pragma unroll
    for (int i = 0; i < 4; i++)
        out[i] = f2b((xv[i] - mu) * inv * gv[i] + bv[i]);
    *(u16x4*)(xn + (size_t)row * D_MODEL + c0) = out;
}

// ---------------- merged prep: LN (lnRows rows) + W cvt + conv_w transpose ----------------
__global__ __launch_bounds__(256) void prep_kernel(
    const float* __restrict__ x, const float* __restrict__ gamma,
    const float* __restrict__ beta, u16* __restrict__ xn,
    const float* __restrict__ W_in, u16* __restrict__ wbin,
    const float* __restrict__ W_out, u16* __restrict__ wbout,
    const float* __restrict__ conv_w, float* __restrict__ wt,
    int lnRows)
{
    const int b   = blockIdx.x;
    const int tid = threadIdx.x;

    if (b < lnRows) {
        ln_body(b, tid, x, gamma, beta, xn);
        return;
    }
    int rb = b - lnRows;
    if (rb < 4096) {                       // W_in convert
        const int o = (rb * 256 + tid) * 4;
        f32x4 v = *(const f32x4*)(W_in + o);
        u16x4 w;
#pragma unroll
        for (int j = 0; j < 4; j++) w[j] = f2b(v[j]);
        *(u16x4*)(wbin + o) = w;
        return;
    }
    rb -= 4096;
    if (rb < 2048) {                       // W_out convert
        const int o = (rb * 256 + tid) * 4;
        f32x4 v = *(const f32x4*)(W_out + o);
        u16x4 w;
#pragma unroll
        for (int j = 0; j < 4; j++) w[j] = f2b(v[j]);
        *(u16x4*)(wbout + o) = w;
        return;
    }
    rb -= 2048;                            // conv_w transpose (32 blocks)
    const int i = rb * 256 + tid;          // 0..8191
    const int ch = i >> 2, j = i & 3;
    wt[j * D_INNER + ch] = conv_w[i];
}

// ---------------- standalone LN (chunked fallback path) ----------------
__global__ __launch_bounds__(256) void ln_kernel(
    const float* __restrict__ x, const float* __restrict__ gamma,
    const float* __restrict__ beta, u16* __restrict__ xn)
{
    ln_body(blockIdx.x, threadIdx.x, x, gamma, beta, xn);
}

// =====================================================================================
// 256x256 8-phase GEMM: C[M,N] = A[M,K] * Bt[N,K]^T (+fp32 residual)
// 512 thr = 8 waves (2M x 4N), per-wave 128x64 out, BK=64, 2 K-tiles/iter.
// LDS 128 KiB double-buffer; XOR-swizzled global_load_lds source so
// LDS[row][chunk] = G[row][chunk^(row&7)]; ds_read_b128 fragments conflict-free.
// Pipeline (per 4-phase tile; raw s_barriers, counted vmcnt, NO explicit lgkmcnt:
// the compiler emits fine-grained lgkmcnt(N) interleaved into the MFMA cluster,
// overlapping the LDS drain with MFMA — explicit lgkmcnt(0) serialized them):
//   p1: ds B-Nh0(4)+A-Mh0(8); stage next A-odd ; MFMA Q(0,0)
//   p2: ds B-Nh1(4)         ; stage t+2 A-even; MFMA Q(0,2)
//   p3: ds A-Mh1(8)         ; stage t+2 B-even; MFMA Q(4,0)
//   p4:                       stage t+2 B-odd ; MFMA Q(4,2); vmcnt(6)
// WAR safety: every ds_read is consumed by an MFMA before the closing barrier,
// so all reads of phase p are retired chip-wide before any phase-p+1 stage issues.
// =====================================================================================
#define BAR()      __builtin_amdgcn_s_barrier()
#define WAIT_VM6() asm volatile("s_waitcnt vmcnt(6)" ::: "memory")
#define WAIT_VM0() asm volatile("s_waitcnt vmcnt(0)" ::: "memory")

#define STAGE_A(ldsb, s0, s1, kt) do { \
    gld_lds16(Ag + (size_t)(s0) * K + (kt) + goff, &(ldsb)[(s0) * 64]); \
    gld_lds16(Ag + (size_t)(s1) * K + (kt) + goff, &(ldsb)[(s1) * 64]); \
} while (0)
#define STAGE_B(ldsb, s0, s1, kt) do { \
    gld_lds16(Bg + (size_t)(s0) * K + (kt) + goff, &(ldsb)[(s0) * 64]); \
    gld_lds16(Bg + (size_t)(s1) * K + (kt) + goff, &(ldsb)[(s1) * 64]); \
} while (0)

#define RD_A(base, roff) do { \
    _Pragma("unroll") for (int m_ = 0; m_ < 4; m_++) { \
        const u16* p_ = (base) + (arow0 + (roff) + m_ * 16) * 64; \
        aF[m_][0] = __builtin_bit_cast(bf16x8, *(const u16x8*)(p_ + cx0)); \
        aF[m_][1] = __builtin_bit_cast(bf16x8, *(const u16x8*)(p_ + cx1)); \
    } } while (0)
#define RD_B(base, dst, roff) do { \
    _Pragma("unroll") for (int n_ = 0; n_ < 2; n_++) { \
        const u16* p_ = (base) + (brow0 + (roff) + n_ * 16) * 64; \
        dst[n_][0] = __builtin_bit_cast(bf16x8, *(const u16x8*)(p_ + cx0)); \
        dst[n_][1] = __builtin_bit_cast(bf16x8, *(const u16x8*)(p_ + cx1)); \
    } } while (0)

#define MMA_Q(m0, n0, BB) do { \
    _Pragma("unroll") for (int m_ = 0; m_ < 4; m_++) \
    _Pragma("unroll") for (int n_ = 0; n_ < 2; n_++) \
    _Pragma("unroll") for (int k_ = 0; k_ < 2; k_++) \
        acc[(m0) + m_][(n0) + n_] = __builtin_amdgcn_mfma_f32_16x16x32_bf16( \
            aF[m_][k_], BB[n_][k_], acc[(m0) + m_][(n0) + n_], 0, 0, 0); \
} while (0)

template<bool OUT_F32>
__global__ __launch_bounds__(512, 2) void gemm256(
    const u16* __restrict__ A, const u16* __restrict__ Bt,
    void* __restrict__ Cv, const float* __restrict__ Res,
    int M, int N, int K)
{
    __shared__ u16 As[2][256 * 64];
    __shared__ u16 Bs[2][256 * 64];

    const int tid  = threadIdx.x;
    const int wave = tid >> 6;
    const int lane = tid & 63;
    const int wm = wave >> 2, wn = wave & 3;
    const int lane15 = lane & 15, quad = lane >> 4;

    // bijective XCD-aware swizzle (all launch grids have nwg % 8 == 0)
    const int gx   = gridDim.x;
    const int nwg  = gx * gridDim.y;
    const int flat = blockIdx.y * gx + blockIdx.x;
    const int q8   = nwg >> 3;
    const int swz  = (flat & 7) * q8 + (flat >> 3);
    const int bm = swz % gx, bn = swz / gx;

    const u16* Ag = A  + (size_t)bm * 256 * K;
    const u16* Bg = Bt + (size_t)bn * 256 * K;

    // staging: per lane source offset (XOR-swizzled column chunk)
    const int lrow = lane >> 3;                       // 0..7
    const int lcol = ((lane & 7) ^ lrow) * 8;
    const size_t goff = (size_t)lrow * K + lcol;

    // slab bases (wave-uniform) for each half-tile class
    const int aEv0 = wave * 8,      aEv1 = 128 + wave * 8;
    const int aOd0 = 64 + wave * 8, aOd1 = 192 + wave * 8;
    const int bEv0 = (wave >> 2) * 64 + (wave & 3) * 8, bEv1 = 128 + bEv0;
    const int bOd0 = bEv0 + 32,     bOd1 = bEv1 + 32;

    // fragment-read constants
    const int arow0 = wm * 128 + lane15;
    const int brow0 = wn * 64  + lane15;
    const int sw8   = lane15 & 7;
    const int cx0   = ((quad ^ sw8) << 3);   // chunk c=quad
    const int cx1   = cx0 ^ 32;              // chunk c=quad+4

    f32x4  acc[8][4] = {};
    bf16x8 aF[4][2], bE[2][2], bO[2][2];

    const int NT = K >> 6;       // K-tiles (even for K=1024/2048)
    const int NI = NT >> 1;

    // ---- prologue: tile0 full -> buf0; tile1 first 3 halves -> buf1
    STAGE_A(As[0], aEv0, aEv1, 0);
    STAGE_B(Bs[0], bEv0, bEv1, 0);
    STAGE_B(Bs[0], bOd0, bOd1, 0);
    STAGE_A(As[0], aOd0, aOd1, 0);
    STAGE_A(As[1], aEv0, aEv1, 64);
    STAGE_B(Bs[1], bEv0, bEv1, 64);
    STAGE_B(Bs[1], bOd0, bOd1, 64);
    WAIT_VM6();                 // tile0 landed; tile1's 3 halves in flight
    BAR();

    for (int i = 0; i < NI; i++) {
        const int kt0   = i * 128;
        const bool more = (i + 1 < NI);
#pragma unroll
        for (int h = 0; h < 2; h++) {
            const u16* as = As[h];
            const u16* bs = Bs[h];
            const int ktA = kt0 + 64  + h * 64;   // tile 2i+1+h (A-odd, buf h^1)
            const int ktS = kt0 + 128 + h * 64;   // tile 2i+2+h (p2-p4, buf h)
            const bool gA = (h == 0) || more;
            const bool gS = more;

            // ---- phase 1: Q(0,0)   (B reads first: retirement matches MFMA order)
            RD_B(bs, bE, 0);
            RD_A(as, 0);
            if (gA) STAGE_A(As[h ^ 1], aOd0, aOd1, ktA);
            BAR();
            __builtin_amdgcn_s_setprio(1);
            MMA_Q(0, 0, bE);
            __builtin_amdgcn_s_setprio(0);
            BAR();

            // ---- phase 2: Q(0,2)
            RD_B(bs, bO, 32);
            if (gS) STAGE_A(As[h], aEv0, aEv1, ktS);
            BAR();
            __builtin_amdgcn_s_setprio(1);
            MMA_Q(0, 2, bO);
            __builtin_amdgcn_s_setprio(0);
            BAR();

            // ---- phase 3: Q(4,0)
            if (!more && h == 1) WAIT_VM0();  // last tile: A-odd (2 loads, ~5 phases old)
            RD_A(as, 64);
            if (gS) STAGE_B(Bs[h], bEv0, bEv1, ktS);
            BAR();
            __builtin_amdgcn_s_setprio(1);
            MMA_Q(4, 0, bE);
            __builtin_amdgcn_s_setprio(0);
            BAR();

            // ---- phase 4: Q(4,2) + counted drain
            if (gS) STAGE_B(Bs[h], bOd0, bOd1, ktS);
            BAR();
            __builtin_amdgcn_s_setprio(1);
            MMA_Q(4, 2, bO);
            __builtin_amdgcn_s_setprio(0);
            if (more) WAIT_VM6();   // next tile fully landed, 3 halves in flight
            BAR();
        }
    }

    // ---- epilogue: C[row = quad*4+i][col = lane15] per 16x16 subtile
    const int m0 = bm * 256 + wm * 128 + quad * 4;
    const int n0 = bn * 256 + wn * 64 + lane15;
#pragma unroll
    for (int mf = 0; mf < 8; mf++) {
#pragma unroll
        for (int nf = 0; nf < 4; nf++) {
#pragma unroll
            for (int i = 0; i < 4; i++) {
                const int r  = m0 + mf * 16 + i;
                const int cc = n0 + nf * 16;
                const size_t idx = (size_t)r * N + cc;
                float v = acc[mf][nf][i];
                if (OUT_F32) {
                    ((float*)Cv)[idx] = v + Res[idx];
                } else {
                    ((u16*)Cv)[idx] = f2b(v);
                }
            }
        }
    }
}

// ---------------- causal depthwise conv (d_conv=4) + silu(x)*silu(z) ----------------
__global__ __launch_bounds__(256) void conv_gate8(
    const u16* __restrict__ xz, const float* __restrict__ wt,
    const float* __restrict__ conv_b, u16* __restrict__ y)
{
    const int tid  = threadIdx.x;
    const int row0 = blockIdx.x * 8;
    const int c    = tid * 8;
    const int t0   = row0 & (TLEN - 1);

    float w[4][8];
#pragma unroll
    for (int j = 0; j < 4; j++) {
        f32x4 a = *(const f32x4*)(wt + j * D_INNER + c);
        f32x4 b = *(const f32x4*)(wt + j * D_INNER + c + 4);
#pragma unroll
        for (int u = 0; u < 4; u++) { w[j][u] = a[u]; w[j][4 + u] = b[u]; }
    }
    float bias[8];
    {
        f32x4 a = *(const f32x4*)(conv_b + c);
        f32x4 b = *(const f32x4*)(conv_b + c + 4);
#pragma unroll
        for (int u = 0; u < 4; u++) { bias[u] = a[u]; bias[4 + u] = b[u]; }
    }

    u16x8 xv[11];
    if (t0 != 0) {
#pragma unroll
        for (int k = 0; k < 3; k++)
            xv[k] = *(const u16x8*)(xz + (size_t)(row0 - 3 + k) * 4096 + c);
    } else {
#pragma unroll
        for (int k = 0; k < 3; k++) xv[k] = (u16x8)0;
    }
#pragma unroll
    for (int k = 3; k < 11; k++)
        xv[k] = *(const u16x8*)(xz + (size_t)(row0 - 3 + k) * 4096 + c);

#pragma unroll
    for (int i = 0; i < 8; i++) {
        float acc[8];
#pragma unroll
        for (int u = 0; u < 8; u++) acc[u] = bias[u];
#pragma unroll
        for (int j = 0; j < 4; j++)
#pragma unroll
            for (int u = 0; u < 8; u++)
                acc[u] += b2f(xv[i + j][u]) * w[j][u];

        u16x8 zv = *(const u16x8*)(xz + (size_t)(row0 + i) * 4096 + 2048 + c);
        u16x8 out;
#pragma unroll
        for (int u = 0; u < 8; u++) {
            const float a = acc[u];
            const float z = b2f(zv[u]);
            const float sa = a / (1.0f + __expf(-a));
            const float sz = z / (1.0f + __expf(-z));
            out[u] = f2b(sa * sz);
        }
        *(u16x8*)(y + (size_t)(row0 + i) * (size_t)D_INNER + c) = out;
    }
}

extern "C" void kernel_launch(void* const* d_in, const int* in_sizes, int n_in,
                              void* d_out, int out_size, void* d_ws, size_t ws_size,
                              hipStream_t stream)
{
    const float* x      = (const float*)d_in[0];
    const float* gamma  = (const float*)d_in[1];
    const float* beta   = (const float*)d_in[2];
    const float* W_in   = (const float*)d_in[3];  // [4096, 1024] fp32
    const float* conv_w = (const float*)d_in[4];  // [2048, 1, 4] fp32
    const float* conv_b = (const float*)d_in[5];  // [2048] fp32
    const float* W_out  = (const float*)d_in[6];  // [1024, 2048] fp32
    float* out = (float*)d_out;

    const int nWin  = 4096 * 1024;
    const int nWout = 1024 * 2048;
    const int nWc   = D_INNER * 4;            // 8192

    u16*   wbin  = (u16*)d_ws;                // bf16 W_in
    u16*   wbout = wbin + nWin;               // bf16 W_out
    float* wt    = (float*)(wbout + nWout);   // fp32 [4][2048] conv weights
    u16*   base  = (u16*)(wt + nWc);

    // Workspace-adaptive chunking (whole batches -> conv halo never crosses).
    const size_t wbytes = (size_t)(nWin + nWout) * sizeof(u16) + nWc * sizeof(float);
    const size_t perRow = (size_t)(D_MODEL + 4096 + D_INNER) * sizeof(u16);
    int NC = 4;
    if (ws_size >= wbytes + (size_t)NTOK * perRow)          NC = 1;
    else if (ws_size >= wbytes + (size_t)(NTOK/2) * perRow) NC = 2;
    const int RC = NTOK / NC;

    u16* xn = base;                               // RC*1024
    u16* xz = xn + (size_t)RC * D_MODEL;          // RC*4096
    u16* y  = xz + (size_t)RC * 4096;             // RC*2048

    // 0. merged prep: weight cvt (+ full LN when NC==1) — one launch
    const int lnRows = (NC == 1) ? NTOK : 0;
    prep_kernel<<<lnRows + 4096 + 2048 + 32, 256, 0, stream>>>(
        x, gamma, beta, xn, W_in, wbin, W_out, wbout, conv_w, wt, lnRows);

    for (int c = 0; c < NC; c++) {
        const float* xc   = x   + (size_t)c * RC * D_MODEL;
        float*       outc = out + (size_t)c * RC * D_MODEL;

        // 1. LayerNorm (only needed per-chunk when NC>1)
        if (NC > 1)
            ln_kernel<<<RC, 256, 0, stream>>>(xc, gamma, beta, xn);

        // 2. in_proj: xz[RC,4096] = xn[RC,1024] @ W_in^T  (bf16 out)
        dim3 g1(RC / 256, (2 * D_INNER) / 256);
        gemm256<false><<<g1, 512, 0, stream>>>(xn, wbin, xz, nullptr,
                                               RC, 2 * D_INNER, D_MODEL);

        // 3. causal depthwise conv + silu gating (8 tokens/thread)
        conv_gate8<<<RC / 8, 256, 0, stream>>>(xz, wt, conv_b, y);

        // 4. out_proj + residual: out[RC,1024] = x + y[RC,2048] @ W_out^T (fp32 out)
        dim3 g2(RC / 256, D_MODEL / 256);
        gemm256<true><<<g2, 512, 0, stream>>>(y, wbout, outc, xc,
                                              RC, D_MODEL, D_INNER);
    }
}

// Round 4
// 389.558 us; speedup vs baseline: 1.1480x; 1.0292x over previous
//
#include <hip/hip_runtime.h>
#include <hip/hip_bf16.h>

#define D_MODEL 1024
#define D_INNER 2048
#define NTOK    16384   // B*T = 4*4096
#define TLEN    4096
#define LN_EPS  1e-5f

typedef unsigned short u16;
typedef unsigned short u16x4 __attribute__((ext_vector_type(4)));
typedef unsigned short u16x8 __attribute__((ext_vector_type(8)));
typedef __bf16        bf16x8 __attribute__((ext_vector_type(8)));
typedef float         f32x4  __attribute__((ext_vector_type(4)));

__device__ __forceinline__ float b2f(u16 u) {
    union { float f; unsigned int i; } v; v.i = ((unsigned int)u) << 16; return v.f;
}
__device__ __forceinline__ u16 f2b(float f) {
    union { float f; unsigned int i; } v; v.f = f;
    unsigned int r = v.i + 0x7fffu + ((v.i >> 16) & 1u);  // RNE
    return (u16)(r >> 16);
}

// async global->LDS, 16B per lane. LDS dest = wave-uniform base + lane*16.
__device__ __forceinline__ void gld_lds16(const u16* g, u16* l) {
    __builtin_amdgcn_global_load_lds(
        (const __attribute__((address_space(1))) void*)g,
        (__attribute__((address_space(3))) void*)l, 16, 0, 0);
}

// ---------------- LayerNorm body (fp32 in, bf16 out), one block per row ----------------
__device__ __forceinline__ void ln_body(
    int row, int tid,
    const float* __restrict__ x, const float* __restrict__ gamma,
    const float* __restrict__ beta, u16* __restrict__ xn)
{
    const float* xr = x + (size_t)row * D_MODEL;
    const int c0 = tid * 4;

    f32x4 xv = *(const f32x4*)(xr + c0);
    float s = 0.f, s2 = 0.f;
#pragma unroll
    for (int i = 0; i < 4; i++) { s += xv[i]; s2 += xv[i] * xv[i]; }

#pragma unroll
    for (int off = 32; off > 0; off >>= 1) {
        s  += __shfl_down(s,  off);
        s2 += __shfl_down(s2, off);
    }
    __shared__ float red[8];
    const int wave = tid >> 6, lane = tid & 63;
    if (lane == 0) { red[wave] = s; red[4 + wave] = s2; }
    __syncthreads();
    const float ts  = red[0] + red[1] + red[2] + red[3];
    const float ts2 = red[4] + red[5] + red[6] + red[7];
    const float mu  = ts * (1.0f / D_MODEL);
    const float var = ts2 * (1.0f / D_MODEL) - mu * mu;
    const float inv = rsqrtf(var + LN_EPS);

    f32x4 gv = *(const f32x4*)(gamma + c0);
    f32x4 bv = *(const f32x4*)(beta + c0);
    u16x4 out;
#pragma unroll
    for (int i = 0; i < 4; i++)
        out[i] = f2b((xv[i] - mu) * inv * gv[i] + bv[i]);
    *(u16x4*)(xn + (size_t)row * D_MODEL + c0) = out;
}

// ---------------- merged prep: LN (lnRows rows) + W cvt + conv_w transpose ----------------
__global__ __launch_bounds__(256) void prep_kernel(
    const float* __restrict__ x, const float* __restrict__ gamma,
    const float* __restrict__ beta, u16* __restrict__ xn,
    const float* __restrict__ W_in, u16* __restrict__ wbin,
    const float* __restrict__ W_out, u16* __restrict__ wbout,
    const float* __restrict__ conv_w, float* __restrict__ wt,
    int lnRows)
{
    const int b   = blockIdx.x;
    const int tid = threadIdx.x;

    if (b < lnRows) {
        ln_body(b, tid, x, gamma, beta, xn);
        return;
    }
    int rb = b - lnRows;
    if (rb < 4096) {                       // W_in convert
        const int o = (rb * 256 + tid) * 4;
        f32x4 v = *(const f32x4*)(W_in + o);
        u16x4 w;
#pragma unroll
        for (int j = 0; j < 4; j++) w[j] = f2b(v[j]);
        *(u16x4*)(wbin + o) = w;
        return;
    }
    rb -= 4096;
    if (rb < 2048) {                       // W_out convert
        const int o = (rb * 256 + tid) * 4;
        f32x4 v = *(const f32x4*)(W_out + o);
        u16x4 w;
#pragma unroll
        for (int j = 0; j < 4; j++) w[j] = f2b(v[j]);
        *(u16x4*)(wbout + o) = w;
        return;
    }
    rb -= 2048;                            // conv_w transpose (32 blocks)
    const int i = rb * 256 + tid;          // 0..8191
    const int ch = i >> 2, j = i & 3;
    wt[j * D_INNER + ch] = conv_w[i];
}

// ---------------- standalone LN (chunked fallback path) ----------------
__global__ __launch_bounds__(256) void ln_kernel(
    const float* __restrict__ x, const float* __restrict__ gamma,
    const float* __restrict__ beta, u16* __restrict__ xn)
{
    ln_body(blockIdx.x, threadIdx.x, x, gamma, beta, xn);
}

// =====================================================================================
// 256x256 pipelined GEMM: C[M,N] = A[M,K] * Bt[N,K]^T (+fp32 residual)
// 512 thr = 8 waves (2M x 4N), per-wave 128x64 out, BK=64, 2 K-tiles per unrolled pair.
// LDS 128 KiB double-buffer; XOR-swizzled global_load_lds source so
// LDS[row][chunk] = G[row][chunk^(row&7)]; ds_read_b128 fragments conflict-free.
//
// R3/R4: fragment reads are software-pipelined ONE PHASE AHEAD of their consuming MFMA
// (R1/R2 post-mortem: consume-in-same-phase serialized the DS pipe behind the MFMA
// issue cluster -> 38% MfmaUtil ceiling). Quadrant order Q(0,0),Q(0,2),Q(4,0),Q(4,2)
// lets one aF set cover both A-halves; register anti-dependences (MFMA reads old
// aF/bX before the ds_read overwrites them) enforce intra-phase order. One barrier
// per phase. Per tile T (buf = T&1, next = buf^1):
//   P1: vm(8); BAR; read cur.Bh1->bY ; MFMA Q(0,0)[aF=Ah0, bX=Bh0]
//   P2:        BAR; MFMA Q(0,2)[aF,bY]; read cur.Ah1->aF
//   P3: vm(4); BAR; MFMA Q(4,0)[aF,bX]; read next.Bh0->bX; stage T+2 Aev+Bev
//   P4:        BAR; MFMA Q(4,2)[aF,bY]; read next.Ah0->aF; stage T+2 Aod+Bod
// WAR: each region's last ds_read is lgkm-retired before the next phase's MFMA
// (first use), hence published chip-wide >=1 barrier before its restage.
// RAW: vmcnt(8)@P1 covers T-2.P4 stages (cur Ah1/Bh1); vmcnt(4)@P3 covers
// T-1.P3 stages (next Ah0/Bh0). Final tile uses vmcnt(0)@P1 (tail vacuity).
// =====================================================================================
#define BAR()      __builtin_amdgcn_s_barrier()
#define WAIT_VM8() asm volatile("s_waitcnt vmcnt(8)" ::: "memory")
#define WAIT_VM4() asm volatile("s_waitcnt vmcnt(4)" ::: "memory")
#define WAIT_VM0() asm volatile("s_waitcnt vmcnt(0)" ::: "memory")

#define STAGE_A(ldsb, s0, s1, kt) do { \
    gld_lds16(Ag + (size_t)(s0) * K + (kt) + goff, &(ldsb)[(s0) * 64]); \
    gld_lds16(Ag + (size_t)(s1) * K + (kt) + goff, &(ldsb)[(s1) * 64]); \
} while (0)
#define STAGE_B(ldsb, s0, s1, kt) do { \
    gld_lds16(Bg + (size_t)(s0) * K + (kt) + goff, &(ldsb)[(s0) * 64]); \
    gld_lds16(Bg + (size_t)(s1) * K + (kt) + goff, &(ldsb)[(s1) * 64]); \
} while (0)

#define RD_A(base, roff) do { \
    _Pragma("unroll") for (int m_ = 0; m_ < 4; m_++) { \
        const u16* p_ = (base) + (arow0 + (roff) + m_ * 16) * 64; \
        aF[m_][0] = __builtin_bit_cast(bf16x8, *(const u16x8*)(p_ + cx0)); \
        aF[m_][1] = __builtin_bit_cast(bf16x8, *(const u16x8*)(p_ + cx1)); \
    } } while (0)
#define RD_B(base, dst, roff) do { \
    _Pragma("unroll") for (int n_ = 0; n_ < 2; n_++) { \
        const u16* p_ = (base) + (brow0 + (roff) + n_ * 16) * 64; \
        dst[n_][0] = __builtin_bit_cast(bf16x8, *(const u16x8*)(p_ + cx0)); \
        dst[n_][1] = __builtin_bit_cast(bf16x8, *(const u16x8*)(p_ + cx1)); \
    } } while (0)

#define MMA_Q(m0, n0, BB) do { \
    __builtin_amdgcn_s_setprio(1); \
    _Pragma("unroll") for (int m_ = 0; m_ < 4; m_++) \
    _Pragma("unroll") for (int n_ = 0; n_ < 2; n_++) \
    _Pragma("unroll") for (int k_ = 0; k_ < 2; k_++) \
        acc[(m0) + m_][(n0) + n_] = __builtin_amdgcn_mfma_f32_16x16x32_bf16( \
            aF[m_][k_], BB[n_][k_], acc[(m0) + m_][(n0) + n_], 0, 0, 0); \
    __builtin_amdgcn_s_setprio(0); \
} while (0)

template<bool OUT_F32>
__global__ __launch_bounds__(512, 2) void gemm256(
    const u16* __restrict__ A, const u16* __restrict__ Bt,
    void* __restrict__ Cv, const float* __restrict__ Res,
    int M, int N, int K)
{
    __shared__ u16 As[2][256 * 64];
    __shared__ u16 Bs[2][256 * 64];

    const int tid  = threadIdx.x;
    const int wave = tid >> 6;
    const int lane = tid & 63;
    const int wm = wave >> 2, wn = wave & 3;
    const int lane15 = lane & 15, quad = lane >> 4;

    // bijective XCD-aware swizzle (all launch grids have nwg % 8 == 0)
    const int gx   = gridDim.x;
    const int nwg  = gx * gridDim.y;
    const int flat = blockIdx.y * gx + blockIdx.x;
    const int q8   = nwg >> 3;
    const int swz  = (flat & 7) * q8 + (flat >> 3);
    const int bm = swz % gx, bn = swz / gx;

    const u16* Ag = A  + (size_t)bm * 256 * K;
    const u16* Bg = Bt + (size_t)bn * 256 * K;

    // staging: per lane source offset (XOR-swizzled column chunk)
    const int lrow = lane >> 3;                       // 0..7
    const int lcol = ((lane & 7) ^ lrow) * 8;
    const size_t goff = (size_t)lrow * K + lcol;

    // slab bases (wave-uniform) for each half-tile class
    // Aev rows = {0..63,128..191} = A frag-half 0; Aod = A frag-half 1
    // Bev rows = {r: (r&63)<32}   = B n-half 0;    Bod = B n-half 1
    const int aEv0 = wave * 8,      aEv1 = 128 + wave * 8;
    const int aOd0 = 64 + wave * 8, aOd1 = 192 + wave * 8;
    const int bEv0 = (wave >> 2) * 64 + (wave & 3) * 8, bEv1 = 128 + bEv0;
    const int bOd0 = bEv0 + 32,     bOd1 = bEv1 + 32;

    // fragment-read constants
    const int arow0 = wm * 128 + lane15;
    const int brow0 = wn * 64  + lane15;
    const int sw8   = lane15 & 7;
    const int cx0   = ((quad ^ sw8) << 3);   // chunk c=quad
    const int cx1   = cx0 ^ 32;              // chunk c=quad+4

    f32x4  acc[8][4] = {};
    bf16x8 aF[4][2], bX[2][2], bY[2][2];

    const int NT = K >> 6;       // K-tiles (even for K=1024/2048)
    const int NI = NT >> 1;

    // ---- prologue: tile0 -> buf0, tile1 -> buf1; drain; preload aF/bX
    STAGE_A(As[0], aEv0, aEv1, 0);
    STAGE_B(Bs[0], bEv0, bEv1, 0);
    STAGE_A(As[0], aOd0, aOd1, 0);
    STAGE_B(Bs[0], bOd0, bOd1, 0);
    STAGE_A(As[1], aEv0, aEv1, 64);
    STAGE_B(Bs[1], bEv0, bEv1, 64);
    STAGE_A(As[1], aOd0, aOd1, 64);
    STAGE_B(Bs[1], bOd0, bOd1, 64);
    WAIT_VM0();
    BAR();
    RD_A(As[0], 0);          // aF <- tile0.Ah0
    RD_B(Bs[0], bX, 0);      // bX <- tile0.Bh0

    for (int i = 0; i < NI; i++) {
        const bool more = (i + 1 < NI);
#pragma unroll
        for (int h = 0; h < 2; h++) {
            u16* as  = As[h];
            u16* bs  = Bs[h];
            const u16* asn = As[h ^ 1];
            const u16* bsn = Bs[h ^ 1];
            const int ktS  = i * 128 + 128 + h * 64;  // k-offset of tile T+2
            const bool gN  = (h == 0) || more;        // next-tile frag reads
            const bool gS  = more;                    // stage tile T+2
            const bool lastT = (h == 1) && !more;

            // ---- P1
            if (lastT) WAIT_VM0(); else WAIT_VM8();
            BAR();
            RD_B(bs, bY, 32);                 // cur.Bh1 (used P2)
            MMA_Q(0, 0, bX);                  // [aF=Ah0, bX=Bh0]

            // ---- P2
            BAR();
            MMA_Q(0, 2, bY);                  // [aF=Ah0, bY=Bh1]
            RD_A(as, 64);                     // aF <- cur.Ah1 (anti-dep after MFMA)

            // ---- P3
            if (!lastT) WAIT_VM4();
            BAR();
            MMA_Q(4, 0, bX);                  // [aF=Ah1, bX=Bh0-old]
            if (gN) RD_B(bsn, bX, 0);         // bX <- next.Bh0 (anti-dep)
            if (gS) { STAGE_A(as, aEv0, aEv1, ktS); STAGE_B(bs, bEv0, bEv1, ktS); }

            // ---- P4
            BAR();
            MMA_Q(4, 2, bY);                  // [aF=Ah1, bY=Bh1]
            if (gN) RD_A(asn, 0);             // aF <- next.Ah0 (anti-dep)
            if (gS) { STAGE_A(as, aOd0, aOd1, ktS); STAGE_B(bs, bOd0, bOd1, ktS); }
        }
    }

    // ---- epilogue: C[row = quad*4+i][col = lane15] per 16x16 subtile
    const int m0 = bm * 256 + wm * 128 + quad * 4;
    const int n0 = bn * 256 + wn * 64 + lane15;
#pragma unroll
    for (int mf = 0; mf < 8; mf++) {
#pragma unroll
        for (int nf = 0; nf < 4; nf++) {
#pragma unroll
            for (int i = 0; i < 4; i++) {
                const int r  = m0 + mf * 16 + i;
                const int cc = n0 + nf * 16;
                const size_t idx = (size_t)r * N + cc;
                float v = acc[mf][nf][i];
                if (OUT_F32) {
                    ((float*)Cv)[idx] = v + Res[idx];
                } else {
                    ((u16*)Cv)[idx] = f2b(v);
                }
            }
        }
    }
}

// ---------------- causal depthwise conv (d_conv=4) + silu(x)*silu(z) ----------------
__global__ __launch_bounds__(256) void conv_gate8(
    const u16* __restrict__ xz, const float* __restrict__ wt,
    const float* __restrict__ conv_b, u16* __restrict__ y)
{
    const int tid  = threadIdx.x;
    const int row0 = blockIdx.x * 8;
    const int c    = tid * 8;
    const int t0   = row0 & (TLEN - 1);

    float w[4][8];
#pragma unroll
    for (int j = 0; j < 4; j++) {
        f32x4 a = *(const f32x4*)(wt + j * D_INNER + c);
        f32x4 b = *(const f32x4*)(wt + j * D_INNER + c + 4);
#pragma unroll
        for (int u = 0; u < 4; u++) { w[j][u] = a[u]; w[j][4 + u] = b[u]; }
    }
    float bias[8];
    {
        f32x4 a = *(const f32x4*)(conv_b + c);
        f32x4 b = *(const f32x4*)(conv_b + c + 4);
#pragma unroll
        for (int u = 0; u < 4; u++) { bias[u] = a[u]; bias[4 + u] = b[u]; }
    }

    u16x8 xv[11];
    if (t0 != 0) {
#pragma unroll
        for (int k = 0; k < 3; k++)
            xv[k] = *(const u16x8*)(xz + (size_t)(row0 - 3 + k) * 4096 + c);
    } else {
#pragma unroll
        for (int k = 0; k < 3; k++) xv[k] = (u16x8)0;
    }
#pragma unroll
    for (int k = 3; k < 11; k++)
        xv[k] = *(const u16x8*)(xz + (size_t)(row0 - 3 + k) * 4096 + c);

#pragma unroll
    for (int i = 0; i < 8; i++) {
        float acc[8];
#pragma unroll
        for (int u = 0; u < 8; u++) acc[u] = bias[u];
#pragma unroll
        for (int j = 0; j < 4; j++)
#pragma unroll
            for (int u = 0; u < 8; u++)
                acc[u] += b2f(xv[i + j][u]) * w[j][u];

        u16x8 zv = *(const u16x8*)(xz + (size_t)(row0 + i) * 4096 + 2048 + c);
        u16x8 out;
#pragma unroll
        for (int u = 0; u < 8; u++) {
            const float a = acc[u];
            const float z = b2f(zv[u]);
            const float sa = a / (1.0f + __expf(-a));
            const float sz = z / (1.0f + __expf(-z));
            out[u] = f2b(sa * sz);
        }
        *(u16x8*)(y + (size_t)(row0 + i) * (size_t)D_INNER + c) = out;
    }
}

extern "C" void kernel_launch(void* const* d_in, const int* in_sizes, int n_in,
                              void* d_out, int out_size, void* d_ws, size_t ws_size,
                              hipStream_t stream)
{
    const float* x      = (const float*)d_in[0];
    const float* gamma  = (const float*)d_in[1];
    const float* beta   = (const float*)d_in[2];
    const float* W_in   = (const float*)d_in[3];  // [4096, 1024] fp32
    const float* conv_w = (const float*)d_in[4];  // [2048, 1, 4] fp32
    const float* conv_b = (const float*)d_in[5];  // [2048] fp32
    const float* W_out  = (const float*)d_in[6];  // [1024, 2048] fp32
    float* out = (float*)d_out;

    const int nWin  = 4096 * 1024;
    const int nWout = 1024 * 2048;
    const int nWc   = D_INNER * 4;            // 8192

    u16*   wbin  = (u16*)d_ws;                // bf16 W_in
    u16*   wbout = wbin + nWin;               // bf16 W_out
    float* wt    = (float*)(wbout + nWout);   // fp32 [4][2048] conv weights
    u16*   base  = (u16*)(wt + nWc);

    // Workspace-adaptive chunking (whole batches -> conv halo never crosses).
    const size_t wbytes = (size_t)(nWin + nWout) * sizeof(u16) + nWc * sizeof(float);
    const size_t perRow = (size_t)(D_MODEL + 4096 + D_INNER) * sizeof(u16);
    int NC = 4;
    if (ws_size >= wbytes + (size_t)NTOK * perRow)          NC = 1;
    else if (ws_size >= wbytes + (size_t)(NTOK/2) * perRow) NC = 2;
    const int RC = NTOK / NC;

    u16* xn = base;                               // RC*1024
    u16* xz = xn + (size_t)RC * D_MODEL;          // RC*4096
    u16* y  = xz + (size_t)RC * 4096;             // RC*2048

    // 0. merged prep: weight cvt (+ full LN when NC==1) — one launch
    const int lnRows = (NC == 1) ? NTOK : 0;
    prep_kernel<<<lnRows + 4096 + 2048 + 32, 256, 0, stream>>>(
        x, gamma, beta, xn, W_in, wbin, W_out, wbout, conv_w, wt, lnRows);

    for (int c = 0; c < NC; c++) {
        const float* xc   = x   + (size_t)c * RC * D_MODEL;
        float*       outc = out + (size_t)c * RC * D_MODEL;

        // 1. LayerNorm (only needed per-chunk when NC>1)
        if (NC > 1)
            ln_kernel<<<RC, 256, 0, stream>>>(xc, gamma, beta, xn);

        // 2. in_proj: xz[RC,4096] = xn[RC,1024] @ W_in^T  (bf16 out)
        dim3 g1(RC / 256, (2 * D_INNER) / 256);
        gemm256<false><<<g1, 512, 0, stream>>>(xn, wbin, xz, nullptr,
                                               RC, 2 * D_INNER, D_MODEL);

        // 3. causal depthwise conv + silu gating (8 tokens/thread)
        conv_gate8<<<RC / 8, 256, 0, stream>>>(xz, wt, conv_b, y);

        // 4. out_proj + residual: out[RC,1024] = x + y[RC,2048] @ W_out^T (fp32 out)
        dim3 g2(RC / 256, D_MODEL / 256);
        gemm256<true><<<g2, 512, 0, stream>>>(y, wbout, outc, xc,
                                              RC, D_MODEL, D_INNER);
    }
}